// Round 7
// baseline (216.170 us; speedup 1.0000x reference)
//
#include <hip/hip_runtime.h>
#include <hip/hip_bf16.h>

#define N_NODES 100000
#define N_EDGES 1600000
#define D 128
#define NEG_SLOPE 0.2f

#define NBKT 782          // ceil(100000/128) buckets of 128 nodes
#define CAPB 4096         // fixed eb capacity per bucket (mean 2046, +45 sigma)
#define BCHUNK 4096       // edges per bin block
#define BIN_BLOCKS 391    // ceil(1600000/4096)
#define GEMM_BLOCKS 782   // ceil(100000/128)
#define CAP 2816          // aggregate LDS sort capacity (17 sigma)

typedef __attribute__((ext_vector_type(8))) short s8v;   // 8 bf16 = 4 VGPRs
typedef __attribute__((ext_vector_type(4))) float f4v;   // MFMA acc

static __device__ __forceinline__ unsigned short f2bf(float f) {
    __hip_bfloat16 b = __float2bfloat16(f);
    return *(unsigned short*)&b;
}
static __device__ __forceinline__ float bflo(unsigned int u) {
    return __uint_as_float(u << 16);
}
static __device__ __forceinline__ float bfhi(unsigned int u) {
    return __uint_as_float(u & 0xffff0000u);
}

// ---------------------------------------------------------------------------
// Kernel 0: wcast — one block. Wt[n][k] = bf16(W[k][n]) for n<128;
// Wt[128][k] / Wt[129][k] = bf16(W @ attn_l / attn_r)  (el/er as GEMM cols).
// ---------------------------------------------------------------------------
__global__ __launch_bounds__(256) void wcast(
    const float* __restrict__ W, const float* __restrict__ attn_l,
    const float* __restrict__ attn_r, unsigned short* __restrict__ Wt)
{
    __shared__ float Wl[128 * 132];   // +4 pad
    __shared__ float all[128], arl[128];
    const int t = threadIdx.x;
    for (int i = 0; i < 64; ++i) {
        const int id = t + 256 * i;
        Wl[(id >> 7) * 132 + (id & 127)] = W[id];
    }
    if (t < 128) { all[t] = attn_l[t]; arl[t] = attn_r[t]; }
    __syncthreads();
    for (int i = 0; i < 64; ++i) {
        const int id = t + 256 * i;
        const int n = id >> 7, k = id & 127;
        Wt[n * 128 + k] = f2bf(Wl[k * 132 + n]);
    }
    if (t < 128) {
        float sl = 0.f, sr = 0.f;
        for (int n = 0; n < 128; ++n) {
            const float v = Wl[t * 132 + n];
            sl += v * all[n]; sr += v * arl[n];
        }
        Wt[128 * 128 + t] = f2bf(sl);
        Wt[129 * 128 + t] = f2bf(sr);
    }
}

// ---------------------------------------------------------------------------
// Kernel 1: fused gemm+bin (independent work, one dispatch so they overlap).
// Blocks [0, BIN_BLOCKS) = bin; the rest = MFMA GEMM. LDS arena 38 KB ->
// 4 blocks/CU (2048-thread cap), 32 waves/CU.
// GEMM path loads A-fragments DIRECTLY from global (A[m=lane&15][k=quad*8+j]
// = 2x dwordx4 of h per wave per K-step; 16 rows x 128 B = full lines), so
// no A-tile in LDS and one fewer barrier. B staged XOR-swizzled in LDS.
// ---------------------------------------------------------------------------
__global__ __launch_bounds__(512) void gemm_bin(
    const float* __restrict__ h, const unsigned short* __restrict__ Wt,
    unsigned short* __restrict__ featb, float* __restrict__ el, float* __restrict__ er,
    const int* __restrict__ src, const int* __restrict__ dst,
    int* __restrict__ gwp, unsigned int* __restrict__ eb)
{
    __shared__ __align__(16) char smem[38144];
    const int t = threadIdx.x;

    if (blockIdx.x < BIN_BLOCKS) {
        // ------------------- bin path -------------------
        int* cnt_l            = (int*)smem;                       // 782
        int* lbase            = (int*)(smem + 3136);              // 783
        int* gbase            = (int*)(smem + 6272);              // 782
        int* tmp              = (int*)(smem + 9408);              // 1024
        unsigned int* slocal  = (unsigned int*)(smem + 13504);    // 4096
        unsigned short* sbkt  = (unsigned short*)(smem + 29888);  // 4096

        const int base = (int)blockIdx.x * BCHUNK;
        const int nloc = min(BCHUNK, N_EDGES - base);

        for (int i = t; i < NBKT; i += 512) cnt_l[i] = 0;
        __syncthreads();

        unsigned int ent[8];
        unsigned short bk[8];
#pragma unroll
        for (int j = 0; j < 8; ++j) {
            const int i = t + 512 * j;
            if (i < nloc) {
                const int s = src[base + i];
                const int d = dst[base + i];
                bk[j]  = (unsigned short)(d >> 7);
                ent[j] = (unsigned int)s | ((unsigned int)(d & 127) << 17);
                atomicAdd(&cnt_l[bk[j]], 1);
            } else bk[j] = 0xffff;
        }
        __syncthreads();

        tmp[t]       = (t < NBKT) ? cnt_l[t] : 0;
        tmp[t + 512] = (t + 512 < NBKT) ? cnt_l[t + 512] : 0;
        __syncthreads();
        for (int o = 1; o < 1024; o <<= 1) {
            const int a  = (t >= o) ? tmp[t - o] : 0;
            const int b2 = (t + 512 >= o) ? tmp[t + 512 - o] : 0;
            __syncthreads();
            tmp[t] += a; tmp[t + 512] += b2;
            __syncthreads();
        }
        for (int i = t; i < NBKT; i += 512) lbase[i] = (i == 0) ? 0 : tmp[i - 1];
        if (t == 0) lbase[NBKT] = tmp[NBKT - 1];
        __syncthreads();

        for (int b = t; b < NBKT; b += 512) {
            const int c = lbase[b + 1] - lbase[b];
            if (c) gbase[b] = b * CAPB + atomicAdd(&gwp[b], c);
            cnt_l[b] = 0;
        }
        __syncthreads();

#pragma unroll
        for (int j = 0; j < 8; ++j) {
            if (bk[j] != 0xffff) {
                const int p = lbase[bk[j]] + atomicAdd(&cnt_l[bk[j]], 1);
                slocal[p] = ent[j];
                sbkt[p]   = bk[j];
            }
        }
        __syncthreads();

        for (int i = t; i < nloc; i += 512) {
            const int b = sbkt[i];
            eb[gbase[b] + (i - lbase[b])] = slocal[i];
        }
    } else {
        // ------------------- gemm path -------------------
        unsigned short* Bsmem = (unsigned short*)smem;   // 36 KB (144x128 rows)

        const int w    = t >> 6;
        const int lane = t & 63;
        const int g4   = lane >> 4;
        const int cl   = lane & 15;
        const int row0 = ((int)blockIdx.x - BIN_BLOCKS) * 128;
        const int arow = min(row0 + w * 16 + cl, N_NODES - 1);

        for (int ch = t; ch < 2080; ch += 512) {
            const int n = ch >> 4, c = ch & 15;
            *(s8v*)&Bsmem[n * 128 + ((c ^ (n & 15)) << 3)] =
                *(const s8v*)&Wt[n * 128 + c * 8];
        }
        __syncthreads();

        f4v acc[9] = {};
#pragma unroll
        for (int ks = 0; ks < 4; ++ks) {
            const int c = ks * 4 + g4;
            // A fragment direct from global: h[arow][c*8 .. c*8+7] -> bf16.
            const float4 a0 = *(const float4*)&h[arow * D + c * 8];
            const float4 a1 = *(const float4*)&h[arow * D + c * 8 + 4];
            s8v af;
            af[0] = (short)f2bf(a0.x); af[1] = (short)f2bf(a0.y);
            af[2] = (short)f2bf(a0.z); af[3] = (short)f2bf(a0.w);
            af[4] = (short)f2bf(a1.x); af[5] = (short)f2bf(a1.y);
            af[6] = (short)f2bf(a1.z); af[7] = (short)f2bf(a1.w);
            s8v bfr[9];
#pragma unroll
            for (int nt = 0; nt < 9; ++nt) {
                const int n = nt * 16 + cl;          // n & 15 == cl
                bfr[nt] = *(const s8v*)&Bsmem[n * 128 + ((c ^ cl) << 3)];
            }
#pragma unroll
            for (int nt = 0; nt < 9; ++nt)
                acc[nt] = __builtin_amdgcn_mfma_f32_16x16x32_bf16(
                    af, bfr[nt], acc[nt], 0, 0, 0);
        }

        // Epilogue: acc -> ftile (reuses Bsmem after barrier) -> coalesced
        // bf16 store; el/er straight from col-tile 8 (cols 128/129).
        __syncthreads();
        unsigned short* ftile = Bsmem;   // 32 KB <= 36 KB
#pragma unroll
        for (int nt = 0; nt < 8; ++nt) {
            const int ch = 2 * nt + (cl >> 3);
#pragma unroll
            for (int reg = 0; reg < 4; ++reg) {
                const int r = w * 16 + 4 * g4 + reg;
                ftile[r * 128 + ((ch ^ (r & 15)) << 3) + (cl & 7)] =
                    f2bf(acc[nt][reg]);
            }
        }
        if (cl < 2) {   // col 128 -> el, col 129 -> er
            float* dstp = (cl == 0) ? el : er;
#pragma unroll
            for (int reg = 0; reg < 4; ++reg) {
                const int rg = row0 + w * 16 + 4 * g4 + reg;
                if (rg < N_NODES) dstp[rg] = acc[8][reg];
            }
        }
        __syncthreads();
#pragma unroll
        for (int i = 0; i < 4; ++i) {
            const int ch = t + 512 * i;
            const int r = ch >> 4, c = ch & 15;
            if (row0 + r < N_NODES)
                *(s8v*)&featb[(row0 + r) * 128 + c * 8] =
                    *(const s8v*)&ftile[r * 128 + ((c ^ (r & 15)) << 3)];
        }
    }
}

// ---------------------------------------------------------------------------
// Kernel 2: per-bucket counting sort (LDS) + one-pass edge softmax + bf16
// aggregation. Hot loop quarter-wave restructure: 16 lanes x uint4 (16 B =
// 8 feats) per edge, 4 edges per memory instruction (1 KB/instr), hand-
// unrolled x2 -> 8 edges in flight, 2 sw reads per 8 edges. Per-node loop
// (deg~16) is ~2 iterations; cross-quarter reduce via 2 shfl_xor rounds.
// ---------------------------------------------------------------------------
__global__ __launch_bounds__(512) void aggregate(
    const int* __restrict__ gwp, const unsigned int* __restrict__ eb,
    const float* __restrict__ el, const float* __restrict__ er,
    const uint4* __restrict__ featb4, float* __restrict__ out)
{
    __shared__ __align__(8) uint2 sw[CAP];   // {entry, exp_bits}  22.5 KB
    __shared__ int off_l[129];
    __shared__ int cnt_l[128];
    __shared__ float nsum[128];
    __shared__ float er_l[128];

    const int t = threadIdx.x;
    const int b = blockIdx.x;
    const int ne   = gwp[b];
    const int gbeg = b * CAPB;
    const int node0 = b << 7;
    const int w    = t >> 6;
    const int lane = t & 63;
    const int q    = lane >> 4;    // quarter 0..3
    const int lq   = lane & 15;    // lane-in-quarter; owns feats 8*lq..8*lq+7

    if (t < 128) {
        const int nd = node0 + t;
        er_l[t] = (nd < N_NODES) ? er[nd] : 0.f;
        cnt_l[t] = 0;
        nsum[t] = 0.f;
    }
    __syncthreads();

    if (ne <= CAP) {
        // Pass A: entries to registers + LDS per-node counts.
        unsigned int ent[6];   // ceil(CAP/512) = 6
#pragma unroll
        for (int j = 0; j < 6; ++j) {
            const int i = t + 512 * j;
            if (i < ne) {
                ent[j] = eb[gbeg + i];
                atomicAdd(&cnt_l[(ent[j] >> 17) & 127], 1);
            }
        }
        __syncthreads();
        // Wave-0 scan of the 128 counts.
        if (w == 0) {
            const int a  = cnt_l[2 * lane];
            const int b2 = cnt_l[2 * lane + 1];
            int inc = a + b2;
#pragma unroll
            for (int o = 1; o < 64; o <<= 1) {
                const int u = __shfl_up(inc, o, 64);
                if (lane >= o) inc += u;
            }
            const int excl = inc - (a + b2);
            off_l[2 * lane]     = excl;
            off_l[2 * lane + 1] = excl + a;
            if (lane == 63) off_l[128] = inc;
            cnt_l[2 * lane] = 0; cnt_l[2 * lane + 1] = 0;
        }
        __syncthreads();
        // Pass B: scatter {entry, exp} + accumulate nsum.
#pragma unroll
        for (int j = 0; j < 6; ++j) {
            const int i = t + 512 * j;
            if (i < ne) {
                const unsigned int e = ent[j];
                const int dl = (e >> 17) & 127;
                const int sj = (int)(e & 0x1FFFFu);
                float sc = el[sj] + er_l[dl];
                sc = (sc > 0.f) ? sc : NEG_SLOPE * sc;
                const float ex = __expf(sc);
                const int p = off_l[dl] + atomicAdd(&cnt_l[dl], 1);
                sw[p] = make_uint2(e, __float_as_uint(ex));
                atomicAdd(&nsum[dl], ex);
            }
        }
        __syncthreads();

        // Aggregation: wave w handles nodes dl = w, w+8, ...
        for (int dl = w; dl < 128; dl += 8) {
            const int node = node0 + dl;
            if (node >= N_NODES) break;
            const int beg = off_l[dl];
            const int n   = off_l[dl + 1] - beg;
            float4 accA = make_float4(0.f, 0.f, 0.f, 0.f);
            float4 accB = make_float4(0.f, 0.f, 0.f, 0.f);
            const int iters = (n + 7) >> 3;
            for (int tt = 0; tt < iters; ++tt) {
                const int i0 = 8 * tt + q;
                const int i1 = 8 * tt + 4 + q;
                const uint2 p0 = sw[beg + min(i0, n - 1)];
                const uint2 p1 = sw[beg + min(i1, n - 1)];
                const float w0 = (i0 < n) ? __uint_as_float(p0.y) : 0.f;
                const float w1 = (i1 < n) ? __uint_as_float(p1.y) : 0.f;
                const uint4 f0 = featb4[(p0.x & 0x1FFFFu) * 16 + lq];
                const uint4 f1 = featb4[(p1.x & 0x1FFFFu) * 16 + lq];
                accA.x += w0 * bflo(f0.x); accA.y += w0 * bfhi(f0.x);
                accA.z += w0 * bflo(f0.y); accA.w += w0 * bfhi(f0.y);
                accB.x += w0 * bflo(f0.z); accB.y += w0 * bfhi(f0.z);
                accB.z += w0 * bflo(f0.w); accB.w += w0 * bfhi(f0.w);
                accA.x += w1 * bflo(f1.x); accA.y += w1 * bfhi(f1.x);
                accA.z += w1 * bflo(f1.y); accA.w += w1 * bfhi(f1.y);
                accB.x += w1 * bflo(f1.z); accB.y += w1 * bfhi(f1.z);
                accB.z += w1 * bflo(f1.w); accB.w += w1 * bfhi(f1.w);
            }
            // reduce across quarters (lanes lq, lq+16, lq+32, lq+48)
#pragma unroll
            for (int o = 16; o < 64; o <<= 1) {
                accA.x += __shfl_xor(accA.x, o, 64);
                accA.y += __shfl_xor(accA.y, o, 64);
                accA.z += __shfl_xor(accA.z, o, 64);
                accA.w += __shfl_xor(accA.w, o, 64);
                accB.x += __shfl_xor(accB.x, o, 64);
                accB.y += __shfl_xor(accB.y, o, 64);
                accB.z += __shfl_xor(accB.z, o, 64);
                accB.w += __shfl_xor(accB.w, o, 64);
            }
            const float rs = 1.f / fmaxf(nsum[dl], 1e-9f);
            if (lane < 16) {
                *(float4*)&out[node * D + lq * 8] =
                    make_float4(accA.x * rs, accA.y * rs, accA.z * rs, accA.w * rs);
                *(float4*)&out[node * D + lq * 8 + 4] =
                    make_float4(accB.x * rs, accB.y * rs, accB.z * rs, accB.w * rs);
            }
        }
    } else {
        // Statistically-unreachable fallback (bucket > CAP): direct scan.
        const int ll   = lane & 31;
        const int half = lane >> 5;
        for (int dl = w; dl < 128; dl += 8) {
            const int node = node0 + dl;
            if (node >= N_NODES) break;
            float4 acc = make_float4(0.f, 0.f, 0.f, 0.f);
            float ssum = 0.f;
            for (int ch = 0; ch < ne; ch += 64) {
                const int nn = min(64, ne - ch);
                float ex = 0.f; int sj = 0;
                if (lane < nn) {
                    const unsigned int e = eb[gbeg + ch + lane];
                    if ((int)((e >> 17) & 127) == dl) {
                        sj = (int)(e & 0x1FFFFu);
                        float sc = el[sj] + er_l[dl];
                        sc = (sc > 0.f) ? sc : NEG_SLOPE * sc;
                        ex = __expf(sc);
                    }
                }
                ssum += ex;
                const int iters = (nn + 1) >> 1;
                for (int tt = 0; tt < iters; ++tt) {
                    const int idx = 2 * tt + half;
                    const float wj = __shfl(ex, idx, 64);
                    const int  sjj = __shfl(sj, idx, 64);
                    if (wj > 0.f) {
                        const uint2 fb = ((const uint2*)featb4)[sjj * 32 + ll];
                        acc.x += wj * bflo(fb.x); acc.y += wj * bfhi(fb.x);
                        acc.z += wj * bflo(fb.y); acc.w += wj * bfhi(fb.y);
                    }
                }
            }
#pragma unroll
            for (int o = 1; o < 64; o <<= 1) ssum += __shfl_xor(ssum, o, 64);
            acc.x += __shfl_xor(acc.x, 32, 64);
            acc.y += __shfl_xor(acc.y, 32, 64);
            acc.z += __shfl_xor(acc.z, 32, 64);
            acc.w += __shfl_xor(acc.w, 32, 64);
            const float rs = 1.f / fmaxf(ssum, 1e-9f);
            if (lane < 32)
                *(float4*)&out[node * D + ll * 4] =
                    make_float4(acc.x * rs, acc.y * rs, acc.z * rs, acc.w * rs);
        }
    }
}

// ---------------------------------------------------------------------------
extern "C" void kernel_launch(void* const* d_in, const int* in_sizes, int n_in,
                              void* d_out, int out_size, void* d_ws, size_t ws_size,
                              hipStream_t stream)
{
    const float* h      = (const float*)d_in[0];
    const int*   src    = (const int*)  d_in[1];
    const int*   dst    = (const int*)  d_in[2];
    const float* W      = (const float*)d_in[3];
    const float* attn_l = (const float*)d_in[4];
    const float* attn_r = (const float*)d_in[5];
    float* out = (float*)d_out;

    // Workspace layout (~40 MB).
    char* ws = (char*)d_ws;
    unsigned short* featb = (unsigned short*)ws; ws += (size_t)N_NODES * D * 2;
    unsigned short* Wt    = (unsigned short*)ws; ws += (size_t)130 * 128 * 2;
    ws = (char*)(((size_t)ws + 15) & ~(size_t)15);
    float* el  = (float*)ws; ws += (size_t)N_NODES * sizeof(float);
    float* er  = (float*)ws; ws += (size_t)N_NODES * sizeof(float);
    int*   gwp = (int*)ws;   ws += (size_t)NBKT * sizeof(int);
    ws = (char*)(((size_t)ws + 15) & ~(size_t)15);
    unsigned int* eb = (unsigned int*)ws; ws += (size_t)NBKT * CAPB * sizeof(unsigned int);

    hipMemsetAsync(gwp, 0, (size_t)NBKT * sizeof(int), stream);

    wcast<<<1, 256, 0, stream>>>(W, attn_l, attn_r, Wt);
    gemm_bin<<<BIN_BLOCKS + GEMM_BLOCKS, 512, 0, stream>>>(
        h, Wt, featb, el, er, src, dst, gwp, eb);
    aggregate<<<NBKT, 512, 0, stream>>>(gwp, eb, el, er, (const uint4*)featb, out);
}

// Round 8
// 210.854 us; speedup vs baseline: 1.0252x; 1.0252x over previous
//
#include <hip/hip_runtime.h>
#include <hip/hip_bf16.h>

#define N_NODES 100000
#define N_EDGES 1600000
#define D 128
#define NEG_SLOPE 0.2f

#define NBKT 1563         // ceil(100000/64) buckets of 64 nodes
#define CAPB 2048         // fixed eb capacity per bucket (mean 1024)
#define BCHUNK 4096       // edges per bin block
#define BIN_BLOCKS 391    // ceil(1600000/4096)
#define GEMM_BLOCKS 782   // ceil(100000/128)
#define CAP 1536          // aggregate LDS sort capacity (mean 1024, +16 sigma)

typedef __attribute__((ext_vector_type(8))) short s8v;   // 8 bf16 = 4 VGPRs
typedef __attribute__((ext_vector_type(4))) float f4v;   // MFMA acc

static __device__ __forceinline__ unsigned short f2bf(float f) {
    __hip_bfloat16 b = __float2bfloat16(f);
    return *(unsigned short*)&b;
}
static __device__ __forceinline__ float bflo(unsigned int u) {
    return __uint_as_float(u << 16);
}
static __device__ __forceinline__ float bfhi(unsigned int u) {
    return __uint_as_float(u & 0xffff0000u);
}

// ---------------------------------------------------------------------------
// Kernel 0: wcast — parallelized (17 blocks). Blocks 0-15: transpose slice
// Wt[n][k] = bf16(W[k][n]) for n in [8b, 8b+8). Block 16: Wt[128][k] /
// Wt[129][k] = bf16(W @ attn_l / attn_r)  (el/er as GEMM columns).
// ---------------------------------------------------------------------------
__global__ __launch_bounds__(256) void wcast(
    const float* __restrict__ W, const float* __restrict__ attn_l,
    const float* __restrict__ attn_r, unsigned short* __restrict__ Wt)
{
    const int t = threadIdx.x;
    if (blockIdx.x < 16) {
        const int n0 = blockIdx.x * 8;
#pragma unroll
        for (int i = 0; i < 4; ++i) {
            const int id = t + 256 * i;          // 1024 elems per block
            const int n = n0 + (id >> 7), k = id & 127;
            Wt[n * 128 + k] = f2bf(W[k * 128 + n]);
        }
    } else {
        __shared__ float all[128], arl[128];
        if (t < 128) { all[t] = attn_l[t]; arl[t] = attn_r[t]; }
        __syncthreads();
        if (t < 128) {
            float sl = 0.f, sr = 0.f;
            for (int n = 0; n < 128; ++n) {
                const float v = W[t * 128 + n];
                sl += v * all[n]; sr += v * arl[n];
            }
            Wt[128 * 128 + t] = f2bf(sl);
            Wt[129 * 128 + t] = f2bf(sr);
        }
    }
}

// ---------------------------------------------------------------------------
// Kernel 1: fused gemm+bin (independent work, one dispatch so they overlap).
// Blocks [0, BIN_BLOCKS) = bin; the rest = MFMA GEMM (round-6 A-in-LDS form,
// 68 KB arena -> 2 blocks/CU).
// ---------------------------------------------------------------------------
__global__ __launch_bounds__(512) void gemm_bin(
    const float* __restrict__ h, const unsigned short* __restrict__ Wt,
    unsigned short* __restrict__ featb, float* __restrict__ el, float* __restrict__ er,
    const int* __restrict__ src, const int* __restrict__ dst,
    int* __restrict__ gwp, unsigned int* __restrict__ eb)
{
    __shared__ __align__(16) char smem[69632];
    const int t = threadIdx.x;

    if (blockIdx.x < BIN_BLOCKS) {
        // ------------------- bin path -------------------
        // Bucket = 64 dst nodes (id = d >> 6). Packed entry: src | (d&63)<<17.
        int* cnt_l            = (int*)smem;                       // 1563 (@0)
        int* lbase            = (int*)(smem + 6256);              // 1564
        int* gbase            = (int*)(smem + 12528);             // 1563
        int* tmp              = (int*)(smem + 18784);             // 2048
        unsigned int* slocal  = (unsigned int*)(smem + 26976);    // 4096
        unsigned short* sbkt  = (unsigned short*)(smem + 43360);  // 4096

        const int base = (int)blockIdx.x * BCHUNK;
        const int nloc = min(BCHUNK, N_EDGES - base);

        for (int i = t; i < NBKT; i += 512) cnt_l[i] = 0;
        __syncthreads();

        unsigned int ent[8];
        unsigned short bk[8];
#pragma unroll
        for (int j = 0; j < 8; ++j) {
            const int i = t + 512 * j;
            if (i < nloc) {
                const int s = src[base + i];
                const int d = dst[base + i];
                bk[j]  = (unsigned short)(d >> 6);
                ent[j] = (unsigned int)s | ((unsigned int)(d & 63) << 17);
                atomicAdd(&cnt_l[bk[j]], 1);
            } else bk[j] = 0xffff;
        }
        __syncthreads();

        // Hillis-Steele inclusive scan of 2048 slots (4 per thread).
#pragma unroll
        for (int j = 0; j < 4; ++j) {
            const int i = t + 512 * j;
            tmp[i] = (i < NBKT) ? cnt_l[i] : 0;
        }
        __syncthreads();
        for (int o = 1; o < 2048; o <<= 1) {
            int a[4];
#pragma unroll
            for (int j = 0; j < 4; ++j) {
                const int i = t + 512 * j;
                a[j] = (i >= o) ? tmp[i - o] : 0;
            }
            __syncthreads();
#pragma unroll
            for (int j = 0; j < 4; ++j) tmp[t + 512 * j] += a[j];
            __syncthreads();
        }
        for (int i = t; i < NBKT; i += 512) lbase[i] = (i == 0) ? 0 : tmp[i - 1];
        if (t == 0) lbase[NBKT] = tmp[NBKT - 1];
        __syncthreads();

        for (int b = t; b < NBKT; b += 512) {
            const int c = lbase[b + 1] - lbase[b];
            if (c) gbase[b] = b * CAPB + atomicAdd(&gwp[b], c);
            cnt_l[b] = 0;
        }
        __syncthreads();

#pragma unroll
        for (int j = 0; j < 8; ++j) {
            if (bk[j] != 0xffff) {
                const int p = lbase[bk[j]] + atomicAdd(&cnt_l[bk[j]], 1);
                slocal[p] = ent[j];
                sbkt[p]   = bk[j];
            }
        }
        __syncthreads();

        for (int i = t; i < nloc; i += 512) {
            const int b = sbkt[i];
            eb[gbase[b] + (i - lbase[b])] = slocal[i];
        }
    } else {
        // ------------------- gemm path (round-6) -------------------
        unsigned short* Asmem = (unsigned short*)smem;            // 32 KB
        unsigned short* Bsmem = (unsigned short*)(smem + 32768);  // 36 KB

        const int w    = t >> 6;
        const int lane = t & 63;
        const int g4   = lane >> 4;
        const int cl   = lane & 15;
        const int row0 = ((int)blockIdx.x - BIN_BLOCKS) * 128;

#pragma unroll
        for (int i = 0; i < 4; ++i) {
            const int ch = t + 512 * i;
            const int r = ch >> 4, c = ch & 15;
            const int srow = min(row0 + r, N_NODES - 1);
            const float4 a = *(const float4*)&h[srow * D + c * 8];
            const float4 b = *(const float4*)&h[srow * D + c * 8 + 4];
            s8v v;
            v[0] = (short)f2bf(a.x); v[1] = (short)f2bf(a.y);
            v[2] = (short)f2bf(a.z); v[3] = (short)f2bf(a.w);
            v[4] = (short)f2bf(b.x); v[5] = (short)f2bf(b.y);
            v[6] = (short)f2bf(b.z); v[7] = (short)f2bf(b.w);
            *(s8v*)&Asmem[r * 128 + ((c ^ (r & 15)) << 3)] = v;
        }
        for (int ch = t; ch < 2080; ch += 512) {
            const int n = ch >> 4, c = ch & 15;
            *(s8v*)&Bsmem[n * 128 + ((c ^ (n & 15)) << 3)] =
                *(const s8v*)&Wt[n * 128 + c * 8];
        }
        __syncthreads();

        f4v acc[9] = {};
#pragma unroll
        for (int ks = 0; ks < 4; ++ks) {
            const int c = ks * 4 + g4;
            s8v bfr[9];
#pragma unroll
            for (int nt = 0; nt < 9; ++nt) {
                const int n = nt * 16 + cl;          // n & 15 == cl
                bfr[nt] = *(const s8v*)&Bsmem[n * 128 + ((c ^ cl) << 3)];
            }
            const int r = w * 16 + cl;               // r & 15 == cl
            const s8v af = *(const s8v*)&Asmem[r * 128 + ((c ^ cl) << 3)];
#pragma unroll
            for (int nt = 0; nt < 9; ++nt)
                acc[nt] = __builtin_amdgcn_mfma_f32_16x16x32_bf16(
                    af, bfr[nt], acc[nt], 0, 0, 0);
        }

        // Epilogue: acc -> ftile (reuses Asmem, wave-private rows) -> store.
        unsigned short* ftile = Asmem;
#pragma unroll
        for (int nt = 0; nt < 8; ++nt) {
            const int ch = 2 * nt + (cl >> 3);
#pragma unroll
            for (int reg = 0; reg < 4; ++reg) {
                const int r = w * 16 + 4 * g4 + reg;
                ftile[r * 128 + ((ch ^ (r & 15)) << 3) + (cl & 7)] =
                    f2bf(acc[nt][reg]);
            }
        }
        if (cl < 2) {   // col 128 -> el, col 129 -> er
            float* dstp = (cl == 0) ? el : er;
#pragma unroll
            for (int reg = 0; reg < 4; ++reg) {
                const int rg = row0 + w * 16 + 4 * g4 + reg;
                if (rg < N_NODES) dstp[rg] = acc[8][reg];
            }
        }
        __syncthreads();
#pragma unroll
        for (int i = 0; i < 4; ++i) {
            const int ch = t + 512 * i;
            const int r = ch >> 4, c = ch & 15;
            if (row0 + r < N_NODES)
                *(s8v*)&featb[(row0 + r) * 128 + c * 8] =
                    *(const s8v*)&ftile[r * 128 + ((c ^ (r & 15)) << 3)];
        }
    }
}

// ---------------------------------------------------------------------------
// Kernel 2: per-bucket (64 nodes) counting sort (LDS) + one-pass edge
// softmax + bf16 aggregation. Round-6 half-wave hot loop (known-good):
// 2 edges/iter, 8 B/lane gather, zero shuffles in the loop body.
// 1563 blocks (~6/CU) for occupancy; LDS ~13 KB.
// ---------------------------------------------------------------------------
__global__ __launch_bounds__(512) void aggregate(
    const int* __restrict__ gwp, const unsigned int* __restrict__ eb,
    const float* __restrict__ el, const float* __restrict__ er,
    const uint2* __restrict__ featb2, float* __restrict__ out)
{
    __shared__ __align__(8) uint2 sw[CAP];   // {entry, exp_bits}  12 KB
    __shared__ int off_l[65];
    __shared__ int cnt_l[64];
    __shared__ float nsum[64];
    __shared__ float er_l[64];

    const int t = threadIdx.x;
    const int b = blockIdx.x;
    const int ne   = gwp[b];
    const int gbeg = b * CAPB;
    const int node0 = b << 6;
    const int w    = t >> 6;
    const int lane = t & 63;
    const int ll   = lane & 31;
    const int half = lane >> 5;

    if (t < 64) {
        const int nd = node0 + t;
        er_l[t] = (nd < N_NODES) ? er[nd] : 0.f;
        cnt_l[t] = 0;
        nsum[t] = 0.f;
    }
    __syncthreads();

    if (ne <= CAP) {
        // Pass A: entries to registers + LDS per-node counts.
        unsigned int ent[3];   // ceil(CAP/512) = 3
#pragma unroll
        for (int j = 0; j < 3; ++j) {
            const int i = t + 512 * j;
            if (i < ne) {
                ent[j] = eb[gbeg + i];
                atomicAdd(&cnt_l[(ent[j] >> 17) & 63], 1);
            }
        }
        __syncthreads();
        // Wave-0 scan of the 64 counts (1 per lane).
        if (w == 0) {
            const int v = cnt_l[lane];
            int inc = v;
#pragma unroll
            for (int o = 1; o < 64; o <<= 1) {
                const int u = __shfl_up(inc, o, 64);
                if (lane >= o) inc += u;
            }
            off_l[lane] = inc - v;
            if (lane == 63) off_l[64] = inc;
            cnt_l[lane] = 0;
        }
        __syncthreads();
        // Pass B: scatter {entry, exp} + accumulate nsum.
#pragma unroll
        for (int j = 0; j < 3; ++j) {
            const int i = t + 512 * j;
            if (i < ne) {
                const unsigned int e = ent[j];
                const int dl = (e >> 17) & 63;
                const int sj = (int)(e & 0x1FFFFu);
                float sc = el[sj] + er_l[dl];
                sc = (sc > 0.f) ? sc : NEG_SLOPE * sc;
                const float ex = __expf(sc);
                const int p = off_l[dl] + atomicAdd(&cnt_l[dl], 1);
                sw[p] = make_uint2(e, __float_as_uint(ex));
                atomicAdd(&nsum[dl], ex);
            }
        }
        __syncthreads();

        // Aggregation: wave w handles nodes dl = w, w+8, ... (8 nodes);
        // half-wave h processes edge 2*tt+h; lane ll owns feats 4*ll..4*ll+3.
        for (int dl = w; dl < 64; dl += 8) {
            const int node = node0 + dl;
            if (node >= N_NODES) break;
            const int beg = off_l[dl];
            const int n   = off_l[dl + 1] - beg;
            float4 acc = make_float4(0.f, 0.f, 0.f, 0.f);
            const int iters = (n + 1) >> 1;
            for (int tt = 0; tt < iters; ++tt) {
                const int idx = 2 * tt + half;
                const uint2 p = sw[beg + min(idx, n - 1)];   // b64 broadcast
                const float wj = (idx < n) ? __uint_as_float(p.y) : 0.f;
                const int  sjj = (int)(p.x & 0x1FFFFu);
                const uint2 fb = featb2[sjj * 32 + ll];
                acc.x += wj * bflo(fb.x); acc.y += wj * bfhi(fb.x);
                acc.z += wj * bflo(fb.y); acc.w += wj * bfhi(fb.y);
            }
            acc.x += __shfl_xor(acc.x, 32, 64);
            acc.y += __shfl_xor(acc.y, 32, 64);
            acc.z += __shfl_xor(acc.z, 32, 64);
            acc.w += __shfl_xor(acc.w, 32, 64);
            const float rs = 1.f / fmaxf(nsum[dl], 1e-9f);
            if (lane < 32)
                *(float4*)&out[node * D + ll * 4] =
                    make_float4(acc.x * rs, acc.y * rs, acc.z * rs, acc.w * rs);
        }
    } else {
        // Statistically-unreachable fallback (bucket > CAP): direct scan.
        for (int dl = w; dl < 64; dl += 8) {
            const int node = node0 + dl;
            if (node >= N_NODES) break;
            float4 acc = make_float4(0.f, 0.f, 0.f, 0.f);
            float ssum = 0.f;
            for (int ch = 0; ch < ne; ch += 64) {
                const int nn = min(64, ne - ch);
                float ex = 0.f; int sj = 0;
                if (lane < nn) {
                    const unsigned int e = eb[gbeg + ch + lane];
                    if ((int)((e >> 17) & 63) == dl) {
                        sj = (int)(e & 0x1FFFFu);
                        float sc = el[sj] + er_l[dl];
                        sc = (sc > 0.f) ? sc : NEG_SLOPE * sc;
                        ex = __expf(sc);
                    }
                }
                ssum += ex;
                const int iters = (nn + 1) >> 1;
                for (int tt = 0; tt < iters; ++tt) {
                    const int idx = 2 * tt + half;
                    const float wj = __shfl(ex, idx, 64);
                    const int  sjj = __shfl(sj, idx, 64);
                    if (wj > 0.f) {
                        const uint2 fb = featb2[sjj * 32 + ll];
                        acc.x += wj * bflo(fb.x); acc.y += wj * bfhi(fb.x);
                        acc.z += wj * bflo(fb.y); acc.w += wj * bfhi(fb.y);
                    }
                }
            }
#pragma unroll
            for (int o = 1; o < 64; o <<= 1) ssum += __shfl_xor(ssum, o, 64);
            acc.x += __shfl_xor(acc.x, 32, 64);
            acc.y += __shfl_xor(acc.y, 32, 64);
            acc.z += __shfl_xor(acc.z, 32, 64);
            acc.w += __shfl_xor(acc.w, 32, 64);
            const float rs = 1.f / fmaxf(ssum, 1e-9f);
            if (lane < 32)
                *(float4*)&out[node * D + ll * 4] =
                    make_float4(acc.x * rs, acc.y * rs, acc.z * rs, acc.w * rs);
        }
    }
}

// ---------------------------------------------------------------------------
extern "C" void kernel_launch(void* const* d_in, const int* in_sizes, int n_in,
                              void* d_out, int out_size, void* d_ws, size_t ws_size,
                              hipStream_t stream)
{
    const float* h      = (const float*)d_in[0];
    const int*   src    = (const int*)  d_in[1];
    const int*   dst    = (const int*)  d_in[2];
    const float* W      = (const float*)d_in[3];
    const float* attn_l = (const float*)d_in[4];
    const float* attn_r = (const float*)d_in[5];
    float* out = (float*)d_out;

    // Workspace layout (~40 MB).
    char* ws = (char*)d_ws;
    unsigned short* featb = (unsigned short*)ws; ws += (size_t)N_NODES * D * 2;
    unsigned short* Wt    = (unsigned short*)ws; ws += (size_t)130 * 128 * 2;
    ws = (char*)(((size_t)ws + 15) & ~(size_t)15);
    float* el  = (float*)ws; ws += (size_t)N_NODES * sizeof(float);
    float* er  = (float*)ws; ws += (size_t)N_NODES * sizeof(float);
    int*   gwp = (int*)ws;   ws += (size_t)NBKT * sizeof(int);
    ws = (char*)(((size_t)ws + 15) & ~(size_t)15);
    unsigned int* eb = (unsigned int*)ws; ws += (size_t)NBKT * CAPB * sizeof(unsigned int);

    hipMemsetAsync(gwp, 0, (size_t)NBKT * sizeof(int), stream);

    wcast<<<17, 256, 0, stream>>>(W, attn_l, attn_r, Wt);
    gemm_bin<<<BIN_BLOCKS + GEMM_BLOCKS, 512, 0, stream>>>(
        h, Wt, featb, el, er, src, dst, gwp, eb);
    aggregate<<<NBKT, 512, 0, stream>>>(gwp, eb, el, er, (const uint2*)featb, out);
}

// Round 9
// 196.856 us; speedup vs baseline: 1.0981x; 1.0711x over previous
//
#include <hip/hip_runtime.h>
#include <hip/hip_bf16.h>

#define N_NODES 100000
#define N_EDGES 1600000
#define D 128
#define NEG_SLOPE 0.2f

#define NBKT 1563         // ceil(100000/64) buckets of 64 nodes
#define CAPB 2048         // fixed eb capacity per bucket (mean 1024)
#define BCHUNK 8192       // edges per bin block
#define BIN_BLOCKS 196    // ceil(1600000/8192)
#define GEMM_BLOCKS 782   // ceil(100000/128)
#define CAP 1536          // aggregate LDS sort capacity (mean 1024, +16 sigma)

typedef __attribute__((ext_vector_type(8))) short s8v;   // 8 bf16 = 4 VGPRs
typedef __attribute__((ext_vector_type(4))) float f4v;   // MFMA acc

static __device__ __forceinline__ unsigned short f2bf(float f) {
    __hip_bfloat16 b = __float2bfloat16(f);
    return *(unsigned short*)&b;
}
static __device__ __forceinline__ float bflo(unsigned int u) {
    return __uint_as_float(u << 16);
}
static __device__ __forceinline__ float bfhi(unsigned int u) {
    return __uint_as_float(u & 0xffff0000u);
}

// ---------------------------------------------------------------------------
// Kernel 0: wcast (+ gwp zeroing — replaces the memset dispatch).
// Blocks 0-15: Wt[n][k] = bf16(W[k][n]) slice. Block 16: Wt[128/129][k] =
// bf16(W @ attn_l / attn_r) (el/er as GEMM columns). Blocks 17-18: gwp = 0.
// ---------------------------------------------------------------------------
__global__ __launch_bounds__(256) void wcast(
    const float* __restrict__ W, const float* __restrict__ attn_l,
    const float* __restrict__ attn_r, unsigned short* __restrict__ Wt,
    int* __restrict__ gwp)
{
    const int t = threadIdx.x;
    if (blockIdx.x < 16) {
        const int n0 = blockIdx.x * 8;
#pragma unroll
        for (int i = 0; i < 4; ++i) {
            const int id = t + 256 * i;          // 1024 elems per block
            const int n = n0 + (id >> 7), k = id & 127;
            Wt[n * 128 + k] = f2bf(W[k * 128 + n]);
        }
    } else if (blockIdx.x == 16) {
        __shared__ float all[128], arl[128];
        if (t < 128) { all[t] = attn_l[t]; arl[t] = attn_r[t]; }
        __syncthreads();
        if (t < 128) {
            float sl = 0.f, sr = 0.f;
            for (int n = 0; n < 128; ++n) {
                const float v = W[t * 128 + n];
                sl += v * all[n]; sr += v * arl[n];
            }
            Wt[128 * 128 + t] = f2bf(sl);
            Wt[129 * 128 + t] = f2bf(sr);
        }
    } else {
        const int base = (int)(blockIdx.x - 17) * 800;
        for (int i = t; i < 800; i += 256) {
            const int b = base + i;
            if (b < NBKT) gwp[b] = 0;
        }
    }
}

// ---------------------------------------------------------------------------
// Kernel 1: fused gemm+bin (independent work, one dispatch so they overlap).
// Blocks [0, BIN_BLOCKS) = bin; the rest = MFMA GEMM (68 KB arena, 2 bl/CU).
// Bin: 8192-edge chunk, hierarchical 4-barrier scan (thread-local sum of 4
// buckets -> wave shfl scan -> 8 wave totals -> add back), LDS scatter, one
// reservation atomic per bucket, coalesced-run copy-out (~5.2 edges/run).
// ---------------------------------------------------------------------------
__global__ __launch_bounds__(512) void gemm_bin(
    const float* __restrict__ h, const unsigned short* __restrict__ Wt,
    unsigned short* __restrict__ featb, float* __restrict__ el, float* __restrict__ er,
    const int* __restrict__ src, const int* __restrict__ dst,
    int* __restrict__ gwp, unsigned int* __restrict__ eb)
{
    __shared__ __align__(16) char smem[69632];
    const int t = threadIdx.x;

    if (blockIdx.x < BIN_BLOCKS) {
        // ------------------- bin path -------------------
        // Bucket = 64 dst nodes (id = d >> 6). Packed entry: src | (d&63)<<17.
        int* cnt_l            = (int*)smem;                       // 1563
        int* lbase            = (int*)(smem + 6256);              // 1564
        int* gbase            = (int*)(smem + 12512);             // 1563
        int* wsum             = (int*)(smem + 18768);             // 16
        unsigned int* slocal  = (unsigned int*)(smem + 18832);    // 8192
        unsigned short* sbkt  = (unsigned short*)(smem + 51600);  // 8192

        const int w    = t >> 6;
        const int lane = t & 63;
        const int base = (int)blockIdx.x * BCHUNK;
        const int nloc = min(BCHUNK, N_EDGES - base);

        for (int i = t; i < NBKT; i += 512) cnt_l[i] = 0;
        __syncthreads();

        unsigned int ent[16];
        unsigned short bk[16];
#pragma unroll
        for (int j = 0; j < 16; ++j) {
            const int i = t + 512 * j;
            if (i < nloc) {
                const int s = src[base + i];
                const int d = dst[base + i];
                bk[j]  = (unsigned short)(d >> 6);
                ent[j] = (unsigned int)s | ((unsigned int)(d & 63) << 17);
                atomicAdd(&cnt_l[bk[j]], 1);
            } else bk[j] = 0xffff;
        }
        __syncthreads();

        // Hierarchical exclusive scan of cnt_l[0..NBKT) -> lbase[0..NBKT].
        // Thread t owns slots 4t..4t+3.
        {
            const int i0 = 4 * t;
            const int s0 = (i0 + 0 < NBKT) ? cnt_l[i0 + 0] : 0;
            const int s1 = (i0 + 1 < NBKT) ? cnt_l[i0 + 1] : 0;
            const int s2 = (i0 + 2 < NBKT) ? cnt_l[i0 + 2] : 0;
            const int s3 = (i0 + 3 < NBKT) ? cnt_l[i0 + 3] : 0;
            const int lsum = s0 + s1 + s2 + s3;
            int inc = lsum;
#pragma unroll
            for (int o = 1; o < 64; o <<= 1) {
                const int u = __shfl_up(inc, o, 64);
                if (lane >= o) inc += u;
            }
            if (lane == 63) wsum[w] = inc;
            __syncthreads();
            if (t == 0) {
                int run = 0;
#pragma unroll
                for (int k = 0; k < 8; ++k) { const int v = wsum[k]; wsum[k] = run; run += v; }
            }
            __syncthreads();
            int b0 = wsum[w] + (inc - lsum);   // exclusive prefix of slot i0
            if (i0 + 0 <= NBKT) lbase[i0 + 0] = b0;
            if (i0 + 1 <= NBKT) lbase[i0 + 1] = b0 + s0;
            if (i0 + 2 <= NBKT) lbase[i0 + 2] = b0 + s0 + s1;
            if (i0 + 3 <= NBKT) lbase[i0 + 3] = b0 + s0 + s1 + s2;
        }
        __syncthreads();

        for (int b = t; b < NBKT; b += 512) {
            const int c = lbase[b + 1] - lbase[b];
            if (c) gbase[b] = b * CAPB + atomicAdd(&gwp[b], c);
            cnt_l[b] = 0;
        }
        __syncthreads();

#pragma unroll
        for (int j = 0; j < 16; ++j) {
            if (bk[j] != 0xffff) {
                const int p = lbase[bk[j]] + atomicAdd(&cnt_l[bk[j]], 1);
                slocal[p] = ent[j];
                sbkt[p]   = bk[j];
            }
        }
        __syncthreads();

        for (int i = t; i < nloc; i += 512) {
            const int b = sbkt[i];
            eb[gbase[b] + (i - lbase[b])] = slocal[i];
        }
    } else {
        // ------------------- gemm path (round-6, known-good) -------------------
        unsigned short* Asmem = (unsigned short*)smem;            // 32 KB
        unsigned short* Bsmem = (unsigned short*)(smem + 32768);  // 36 KB

        const int w    = t >> 6;
        const int lane = t & 63;
        const int g4   = lane >> 4;
        const int cl   = lane & 15;
        const int row0 = ((int)blockIdx.x - BIN_BLOCKS) * 128;

#pragma unroll
        for (int i = 0; i < 4; ++i) {
            const int ch = t + 512 * i;
            const int r = ch >> 4, c = ch & 15;
            const int srow = min(row0 + r, N_NODES - 1);
            const float4 a = *(const float4*)&h[srow * D + c * 8];
            const float4 b = *(const float4*)&h[srow * D + c * 8 + 4];
            s8v v;
            v[0] = (short)f2bf(a.x); v[1] = (short)f2bf(a.y);
            v[2] = (short)f2bf(a.z); v[3] = (short)f2bf(a.w);
            v[4] = (short)f2bf(b.x); v[5] = (short)f2bf(b.y);
            v[6] = (short)f2bf(b.z); v[7] = (short)f2bf(b.w);
            *(s8v*)&Asmem[r * 128 + ((c ^ (r & 15)) << 3)] = v;
        }
        for (int ch = t; ch < 2080; ch += 512) {
            const int n = ch >> 4, c = ch & 15;
            *(s8v*)&Bsmem[n * 128 + ((c ^ (n & 15)) << 3)] =
                *(const s8v*)&Wt[n * 128 + c * 8];
        }
        __syncthreads();

        f4v acc[9] = {};
#pragma unroll
        for (int ks = 0; ks < 4; ++ks) {
            const int c = ks * 4 + g4;
            s8v bfr[9];
#pragma unroll
            for (int nt = 0; nt < 9; ++nt) {
                const int n = nt * 16 + cl;          // n & 15 == cl
                bfr[nt] = *(const s8v*)&Bsmem[n * 128 + ((c ^ cl) << 3)];
            }
            const int r = w * 16 + cl;               // r & 15 == cl
            const s8v af = *(const s8v*)&Asmem[r * 128 + ((c ^ cl) << 3)];
#pragma unroll
            for (int nt = 0; nt < 9; ++nt)
                acc[nt] = __builtin_amdgcn_mfma_f32_16x16x32_bf16(
                    af, bfr[nt], acc[nt], 0, 0, 0);
        }

        // Epilogue: acc -> ftile (reuses Asmem, wave-private rows) -> store.
        unsigned short* ftile = Asmem;
#pragma unroll
        for (int nt = 0; nt < 8; ++nt) {
            const int ch = 2 * nt + (cl >> 3);
#pragma unroll
            for (int reg = 0; reg < 4; ++reg) {
                const int r = w * 16 + 4 * g4 + reg;
                ftile[r * 128 + ((ch ^ (r & 15)) << 3) + (cl & 7)] =
                    f2bf(acc[nt][reg]);
            }
        }
        if (cl < 2) {   // col 128 -> el, col 129 -> er
            float* dstp = (cl == 0) ? el : er;
#pragma unroll
            for (int reg = 0; reg < 4; ++reg) {
                const int rg = row0 + w * 16 + 4 * g4 + reg;
                if (rg < N_NODES) dstp[rg] = acc[8][reg];
            }
        }
        __syncthreads();
#pragma unroll
        for (int i = 0; i < 4; ++i) {
            const int ch = t + 512 * i;
            const int r = ch >> 4, c = ch & 15;
            if (row0 + r < N_NODES)
                *(s8v*)&featb[(row0 + r) * 128 + c * 8] =
                    *(const s8v*)&ftile[r * 128 + ((c ^ (r & 15)) << 3)];
        }
    }
}

// ---------------------------------------------------------------------------
// Kernel 2: per-bucket (64 nodes) counting sort (LDS) + one-pass edge
// softmax + bf16 aggregation. Round-8 form (known-good, 75 us): half-wave
// hot loop, 2 edges/iter, 8 B/lane gather, zero shuffles in the body.
// ---------------------------------------------------------------------------
__global__ __launch_bounds__(512) void aggregate(
    const int* __restrict__ gwp, const unsigned int* __restrict__ eb,
    const float* __restrict__ el, const float* __restrict__ er,
    const uint2* __restrict__ featb2, float* __restrict__ out)
{
    __shared__ __align__(8) uint2 sw[CAP];   // {entry, exp_bits}  12 KB
    __shared__ int off_l[65];
    __shared__ int cnt_l[64];
    __shared__ float nsum[64];
    __shared__ float er_l[64];

    const int t = threadIdx.x;
    const int b = blockIdx.x;
    const int ne   = gwp[b];
    const int gbeg = b * CAPB;
    const int node0 = b << 6;
    const int w    = t >> 6;
    const int lane = t & 63;
    const int ll   = lane & 31;
    const int half = lane >> 5;

    if (t < 64) {
        const int nd = node0 + t;
        er_l[t] = (nd < N_NODES) ? er[nd] : 0.f;
        cnt_l[t] = 0;
        nsum[t] = 0.f;
    }
    __syncthreads();

    if (ne <= CAP) {
        // Pass A: entries to registers + LDS per-node counts.
        unsigned int ent[3];   // ceil(CAP/512) = 3
#pragma unroll
        for (int j = 0; j < 3; ++j) {
            const int i = t + 512 * j;
            if (i < ne) {
                ent[j] = eb[gbeg + i];
                atomicAdd(&cnt_l[(ent[j] >> 17) & 63], 1);
            }
        }
        __syncthreads();
        // Wave-0 scan of the 64 counts (1 per lane).
        if (w == 0) {
            const int v = cnt_l[lane];
            int inc = v;
#pragma unroll
            for (int o = 1; o < 64; o <<= 1) {
                const int u = __shfl_up(inc, o, 64);
                if (lane >= o) inc += u;
            }
            off_l[lane] = inc - v;
            if (lane == 63) off_l[64] = inc;
            cnt_l[lane] = 0;
        }
        __syncthreads();
        // Pass B: scatter {entry, exp} + accumulate nsum.
#pragma unroll
        for (int j = 0; j < 3; ++j) {
            const int i = t + 512 * j;
            if (i < ne) {
                const unsigned int e = ent[j];
                const int dl = (e >> 17) & 63;
                const int sj = (int)(e & 0x1FFFFu);
                float sc = el[sj] + er_l[dl];
                sc = (sc > 0.f) ? sc : NEG_SLOPE * sc;
                const float ex = __expf(sc);
                const int p = off_l[dl] + atomicAdd(&cnt_l[dl], 1);
                sw[p] = make_uint2(e, __float_as_uint(ex));
                atomicAdd(&nsum[dl], ex);
            }
        }
        __syncthreads();

        // Aggregation: wave w handles nodes dl = w, w+8, ... (8 nodes);
        // half-wave h processes edge 2*tt+h; lane ll owns feats 4*ll..4*ll+3.
        for (int dl = w; dl < 64; dl += 8) {
            const int node = node0 + dl;
            if (node >= N_NODES) break;
            const int beg = off_l[dl];
            const int n   = off_l[dl + 1] - beg;
            float4 acc = make_float4(0.f, 0.f, 0.f, 0.f);
            const int iters = (n + 1) >> 1;
            for (int tt = 0; tt < iters; ++tt) {
                const int idx = 2 * tt + half;
                const uint2 p = sw[beg + min(idx, n - 1)];   // b64 broadcast
                const float wj = (idx < n) ? __uint_as_float(p.y) : 0.f;
                const int  sjj = (int)(p.x & 0x1FFFFu);
                const uint2 fb = featb2[sjj * 32 + ll];
                acc.x += wj * bflo(fb.x); acc.y += wj * bfhi(fb.x);
                acc.z += wj * bflo(fb.y); acc.w += wj * bfhi(fb.y);
            }
            acc.x += __shfl_xor(acc.x, 32, 64);
            acc.y += __shfl_xor(acc.y, 32, 64);
            acc.z += __shfl_xor(acc.z, 32, 64);
            acc.w += __shfl_xor(acc.w, 32, 64);
            const float rs = 1.f / fmaxf(nsum[dl], 1e-9f);
            if (lane < 32)
                *(float4*)&out[node * D + ll * 4] =
                    make_float4(acc.x * rs, acc.y * rs, acc.z * rs, acc.w * rs);
        }
    } else {
        // Statistically-unreachable fallback (bucket > CAP): direct scan.
        for (int dl = w; dl < 64; dl += 8) {
            const int node = node0 + dl;
            if (node >= N_NODES) break;
            float4 acc = make_float4(0.f, 0.f, 0.f, 0.f);
            float ssum = 0.f;
            for (int ch = 0; ch < ne; ch += 64) {
                const int nn = min(64, ne - ch);
                float ex = 0.f; int sj = 0;
                if (lane < nn) {
                    const unsigned int e = eb[gbeg + ch + lane];
                    if ((int)((e >> 17) & 63) == dl) {
                        sj = (int)(e & 0x1FFFFu);
                        float sc = el[sj] + er_l[dl];
                        sc = (sc > 0.f) ? sc : NEG_SLOPE * sc;
                        ex = __expf(sc);
                    }
                }
                ssum += ex;
                const int iters = (nn + 1) >> 1;
                for (int tt = 0; tt < iters; ++tt) {
                    const int idx = 2 * tt + half;
                    const float wj = __shfl(ex, idx, 64);
                    const int  sjj = __shfl(sj, idx, 64);
                    if (wj > 0.f) {
                        const uint2 fb = featb2[sjj * 32 + ll];
                        acc.x += wj * bflo(fb.x); acc.y += wj * bfhi(fb.x);
                        acc.z += wj * bflo(fb.y); acc.w += wj * bfhi(fb.y);
                    }
                }
            }
#pragma unroll
            for (int o = 1; o < 64; o <<= 1) ssum += __shfl_xor(ssum, o, 64);
            acc.x += __shfl_xor(acc.x, 32, 64);
            acc.y += __shfl_xor(acc.y, 32, 64);
            acc.z += __shfl_xor(acc.z, 32, 64);
            acc.w += __shfl_xor(acc.w, 32, 64);
            const float rs = 1.f / fmaxf(ssum, 1e-9f);
            if (lane < 32)
                *(float4*)&out[node * D + ll * 4] =
                    make_float4(acc.x * rs, acc.y * rs, acc.z * rs, acc.w * rs);
        }
    }
}

// ---------------------------------------------------------------------------
extern "C" void kernel_launch(void* const* d_in, const int* in_sizes, int n_in,
                              void* d_out, int out_size, void* d_ws, size_t ws_size,
                              hipStream_t stream)
{
    const float* h      = (const float*)d_in[0];
    const int*   src    = (const int*)  d_in[1];
    const int*   dst    = (const int*)  d_in[2];
    const float* W      = (const float*)d_in[3];
    const float* attn_l = (const float*)d_in[4];
    const float* attn_r = (const float*)d_in[5];
    float* out = (float*)d_out;

    // Workspace layout (~40 MB).
    char* ws = (char*)d_ws;
    unsigned short* featb = (unsigned short*)ws; ws += (size_t)N_NODES * D * 2;
    unsigned short* Wt    = (unsigned short*)ws; ws += (size_t)130 * 128 * 2;
    ws = (char*)(((size_t)ws + 15) & ~(size_t)15);
    float* el  = (float*)ws; ws += (size_t)N_NODES * sizeof(float);
    float* er  = (float*)ws; ws += (size_t)N_NODES * sizeof(float);
    int*   gwp = (int*)ws;   ws += (size_t)NBKT * sizeof(int);
    ws = (char*)(((size_t)ws + 15) & ~(size_t)15);
    unsigned int* eb = (unsigned int*)ws; ws += (size_t)NBKT * CAPB * sizeof(unsigned int);

    wcast<<<19, 256, 0, stream>>>(W, attn_l, attn_r, Wt, gwp);
    gemm_bin<<<BIN_BLOCKS + GEMM_BLOCKS, 512, 0, stream>>>(
        h, Wt, featb, el, er, src, dst, gwp, eb);
    aggregate<<<NBKT, 512, 0, stream>>>(gwp, eb, el, er, (const uint2*)featb, out);
}